// Round 3
// baseline (11.983 us; speedup 1.0000x reference)
//
#include <hip/hip_runtime.h>
#include <math.h>

// Problem constants from the reference
#define Bn   32
#define Hn   1024
#define Wn   1024
#define NPOS 16
#define NNEG 16
// total point-losses = Bn * (NPOS + NNEG) = 1024; final = sum / 1024

__global__ __launch_bounds__(256) void point_click_loss_kernel(
    const float* __restrict__ mask,   // (B,1,H,W) f32
    const float* __restrict__ pos,    // (B,16,2) f32, (x,y)
    const float* __restrict__ neg,    // (B,16,2) f32
    float* __restrict__ out)          // scalar
{
    const int t = threadIdx.x;        // 0..255, 4 waves
    float sum = 0.0f;

    #pragma unroll
    for (int k = 0; k < 4; ++k) {
        const int l = t + 256 * k;    // loss index 0..1023
        const int b  = l >> 5;        // batch
        const int p  = l & 31;        // point slot
        const bool is_neg = (p >= NPOS);
        const int  pi = p & (NPOS - 1);

        const float* pts = is_neg ? neg : pos;
        const float2 xy = *reinterpret_cast<const float2*>(pts + ((size_t)(b * NPOS + pi)) * 2);
        const float x = xy.x, y = xy.y;

        // Bilinear, align_corners=True: sample at pixel coords directly.
        const float x0f = floorf(x), y0f = floorf(y);
        const float wx1 = x - x0f, wx0 = 1.0f - wx1;
        const float wy1 = y - y0f, wy0 = 1.0f - wy1;

        const int x0 = (int)x0f, y0 = (int)y0f;
        const int x0c = min(max(x0,     0), Wn - 1);
        const int x1c = min(max(x0 + 1, 0), Wn - 1);
        const int y0c = min(max(y0,     0), Hn - 1);
        const int y1c = min(max(y0 + 1, 0), Hn - 1);

        const float* img = mask + (size_t)b * Hn * Wn;
        const float v00 = img[y0c * Wn + x0c];
        const float v01 = img[y0c * Wn + x1c];
        const float v10 = img[y1c * Wn + x0c];
        const float v11 = img[y1c * Wn + x1c];

        const float logit = wy0 * (wx0 * v00 + wx1 * v01)
                          + wy1 * (wx0 * v10 + wx1 * v11);

        // pos: softplus(-logit); neg: softplus(logit). Stable form:
        const float z = is_neg ? logit : -logit;
        sum += fmaxf(z, 0.0f) + log1pf(expf(-fabsf(z)));
    }

    // ---- reduction: 256 threads (4 waves) -> 1 ----
    #pragma unroll
    for (int off = 32; off > 0; off >>= 1)
        sum += __shfl_down(sum, off, 64);

    __shared__ float s[4];
    if ((t & 63) == 0) s[t >> 6] = sum;
    __syncthreads();

    if (t == 0)
        out[0] = (s[0] + s[1] + s[2] + s[3]) * (1.0f / 1024.0f);
}

extern "C" void kernel_launch(void* const* d_in, const int* in_sizes, int n_in,
                              void* d_out, int out_size, void* d_ws, size_t ws_size,
                              hipStream_t stream) {
    const float* mask = (const float*)d_in[0];  // pred_mask (B,1,H,W)
    const float* pos  = (const float*)d_in[1];  // positive_points (B,16,2)
    const float* neg  = (const float*)d_in[2];  // negative_points (B,16,2)
    float* out = (float*)d_out;

    point_click_loss_kernel<<<1, 256, 0, stream>>>(mask, pos, neg, out);
}

// Round 4
// 9.613 us; speedup vs baseline: 1.2465x; 1.2465x over previous
//
#include <hip/hip_runtime.h>
#include <math.h>

// Problem constants from the reference
#define Bn   32
#define Hn   1024
#define Wn   1024
#define NPOS 16
#define NNEG 16
// total point-losses = Bn * (NPOS + NNEG) = 1024; final = sum / 1024
//
// Structure: 1 block, 1024 threads, one (batch,point) loss per thread.
// Latency-bound: point-load -> 4 bilinear taps -> softplus -> block reduce.
// Measured best (R2): ~9.8 us, which is the dispatch/graph-replay floor;
// kernel body itself is sub-microsecond.

__global__ __launch_bounds__(1024) void point_click_loss_kernel(
    const float* __restrict__ mask,   // (B,1,H,W) f32
    const float* __restrict__ pos,    // (B,16,2) f32, (x,y)
    const float* __restrict__ neg,    // (B,16,2) f32
    float* __restrict__ out)          // scalar
{
    const int tid = threadIdx.x;      // 0..1023
    const int b  = tid >> 5;          // batch, 0..31
    const int p  = tid & 31;          // point slot, 0..31
    const bool is_neg = (p >= NPOS);
    const int  pi = p & (NPOS - 1);   // 0..15

    const float* pts = is_neg ? neg : pos;
    const float2 xy = *reinterpret_cast<const float2*>(pts + ((size_t)(b * NPOS + pi)) * 2);
    const float x = xy.x, y = xy.y;

    // Bilinear, align_corners=True semantics: sample at pixel coords directly.
    const float x0f = floorf(x), y0f = floorf(y);
    const float wx1 = x - x0f, wx0 = 1.0f - wx1;
    const float wy1 = y - y0f, wy0 = 1.0f - wy1;

    const int x0 = (int)x0f, y0 = (int)y0f;
    const int x0c = min(max(x0,     0), Wn - 1);
    const int x1c = min(max(x0 + 1, 0), Wn - 1);
    const int y0c = min(max(y0,     0), Hn - 1);
    const int y1c = min(max(y0 + 1, 0), Hn - 1);

    const float* img = mask + (size_t)b * Hn * Wn;
    const float v00 = img[y0c * Wn + x0c];
    const float v01 = img[y0c * Wn + x1c];
    const float v10 = img[y1c * Wn + x0c];
    const float v11 = img[y1c * Wn + x1c];

    const float logit = wy0 * (wx0 * v00 + wx1 * v01)
                      + wy1 * (wx0 * v10 + wx1 * v11);

    // pos: softplus(-logit); neg: softplus(logit). Stable form:
    const float z = is_neg ? logit : -logit;
    float loss = fmaxf(z, 0.0f) + log1pf(expf(-fabsf(z)));

    // ---- block reduction: 1024 -> 1 ----
    #pragma unroll
    for (int off = 32; off > 0; off >>= 1)
        loss += __shfl_down(loss, off, 64);

    __shared__ float s[16];           // 16 waves
    if ((tid & 63) == 0) s[tid >> 6] = loss;
    __syncthreads();

    if (tid < 16) {
        float v = s[tid];
        #pragma unroll
        for (int off = 8; off > 0; off >>= 1)
            v += __shfl_down(v, off, 64);
        if (tid == 0) out[0] = v * (1.0f / 1024.0f);
    }
}

extern "C" void kernel_launch(void* const* d_in, const int* in_sizes, int n_in,
                              void* d_out, int out_size, void* d_ws, size_t ws_size,
                              hipStream_t stream) {
    const float* mask = (const float*)d_in[0];  // pred_mask (B,1,H,W)
    const float* pos  = (const float*)d_in[1];  // positive_points (B,16,2)
    const float* neg  = (const float*)d_in[2];  // negative_points (B,16,2)
    float* out = (float*)d_out;

    point_click_loss_kernel<<<1, 1024, 0, stream>>>(mask, pos, neg, out);
}